// Round 1
// 198.853 us; speedup vs baseline: 1.0040x; 1.0040x over previous
//
#include <hip/hip_runtime.h>

#define Bsz 512
#define Nn  128
#define Dd  256
#define Tt  512

typedef __attribute__((ext_vector_type(8))) short short8;
typedef __attribute__((ext_vector_type(4))) float f32x4;

__device__ __forceinline__ ushort f2bf(float f) {
    union { float f; unsigned u; } v; v.f = f;
    unsigned r = v.u + 0x7fffu + ((v.u >> 16) & 1u);  // RNE
    return (ushort)(r >> 16);
}
__device__ __forceinline__ unsigned pk2(float a, float b) {
    return (unsigned)f2bf(a) | ((unsigned)f2bf(b) << 16);
}
__device__ __forceinline__ float bf2f(ushort u) {
    union { unsigned u; float f; } v; v.u = (unsigned)u << 16; return v.f;
}

// One block per batch, 1024 threads, ~74 KB LDS -> 2 blocks/CU (wave cap).
// v2: split read burst across wave halves, shuffle reductions (no partS),
//     async-stage x re-reads so they drain together with output stores,
//     conflict-free xTp staging writes (uint4 per row, lanes vary row).
__global__ __launch_bounds__(1024, 8) void mega(
    const float* __restrict__ x, const float* __restrict__ adj,
    const int* __restrict__ head, const float* __restrict__ lin_w,
    const float* __restrict__ bias,
    float* __restrict__ emb, float* __restrict__ nadj)
{
    const int b = blockIdx.x, t = threadIdx.x;
    __shared__ __align__(16) ushort adjB[Nn][136];   // 34816 B (-> PT -> xTp)
    __shared__ __align__(16) ushort STl[Nn][136];    // 34816 B
    __shared__ float ttS[Nn], disS[Nn], maskS[Nn], alphaS[Nn], uS[Nn], rowcS[Nn];
    __shared__ float dotL[Nn];
    __shared__ int   flags[Nn];
    __shared__ int   nuniq;
    __shared__ float cutS;

    const float bias0 = bias[0];
    if (t < Nn) flags[t] = 0;
    if (t == 0) { nuniq = 0; cutS = 0.f; }

    // ---- overlapped read burst: waves 0-7 x-dot (+head), waves 8-15 adj ----
    int hv = 0;
    if (t < 512) {
        hv = head[(size_t)b * Tt + t];
        const int dr = t >> 2, dh = t & 3;
        const float4* xr = (const float4*)(x + ((size_t)b * Nn + dr) * Dd + dh * 64);
        const float4* wr = (const float4*)(lin_w + dh * 64);
        float p = 0.f;
#pragma unroll
        for (int i = 0; i < 16; ++i) {
            float4 v = xr[i], w4 = wr[i];
            p += v.x * w4.x + v.y * w4.y + v.z * w4.z + v.w * w4.w;
        }
        p += __shfl_xor(p, 1, 64);
        p += __shfl_xor(p, 2, 64);
        if (dh == 0) dotL[dr] = p;
    } else {
        const int t2 = t - 512;
        const float* adjb = adj + (size_t)b * Nn * Nn;
#pragma unroll
        for (int i = 0; i < 8; ++i) {
            int f = t2 + 512 * i;
            int rr = f >> 5, c = (f & 31) * 4;
            float4 v = *(const float4*)&adjb[(size_t)rr * Nn + c];
            uint2 w2; w2.x = pk2(v.x, v.y); w2.y = pk2(v.z, v.w);
            *(uint2*)&adjB[rr][c] = w2;
        }
    }
    __syncthreads();                                           // B1

    if (t < Tt) flags[hv] = 1;   // consumed after B2

    const int r = t >> 3, seg = t & 7;
    {   // ---- row sums (8 lanes/row, shuffle reduce) ----
        short8 a0 = *(const short8*)&adjB[r][seg * 16];
        short8 a1 = *(const short8*)&adjB[r][seg * 16 + 8];
        float s = 0.f;
#pragma unroll
        for (int j = 0; j < 8; ++j) s += bf2f((ushort)a0[j]) + bf2f((ushort)a1[j]);
        s += __shfl_xor(s, 1, 64);
        s += __shfl_xor(s, 2, 64);
        s += __shfl_xor(s, 4, 64);
        if (seg == 0) {
            maskS[r] = (s > 0.f) ? 1.f : 0.f;
            float dis = 1.f / sqrtf(fmaxf(s + 1.f, 1.f));
            disS[r] = dis;
            ttS[r]  = dis * dotL[r];
        }
    }
    __syncthreads();                                           // B2

    {   // ---- matvec adj*tt -> alpha ----
        short8 a0 = *(const short8*)&adjB[r][seg * 16];
        short8 a1 = *(const short8*)&adjB[r][seg * 16 + 8];
        float s = 0.f;
#pragma unroll
        for (int j = 0; j < 8; ++j) {
            s += bf2f((ushort)a0[j]) * ttS[seg * 16 + j];
            s += bf2f((ushort)a1[j]) * ttS[seg * 16 + 8 + j];
        }
        s += __shfl_xor(s, 1, 64);
        s += __shfl_xor(s, 2, 64);
        s += __shfl_xor(s, 4, 64);
        if (seg == 0) {
            float o = maskS[r] * disS[r] * (s + ttS[r]) + bias0;
            alphaS[r] = 1.f / (1.f + expf(-o * o));
            atomicAdd(&nuniq, flags[r]);
        }
    }
    __syncthreads();                                           // B3

    if (t < Nn) {  // exact k-th largest (rank select; ties like sort)
        int nu = nuniq;
        if (nu > 1) {
            int idx = (int)ceilf((float)nu * 0.1f);
            if (idx > Nn - 1) idx = Nn - 1;
            float an = alphaS[t];
            int cg = 0, ce = 0;
            for (int j = 0; j < Nn; ++j) {
                float aj = alphaS[j];
                cg += (aj > an); ce += (aj == an);
            }
            if (cg <= idx && idx < cg + ce) cutS = an;  // benign same-value race
        }
    }
    __syncthreads();                                           // B4
    if (t < Nn) uS[t] = fmaxf(alphaS[t] + 1e-7f - cutS, 0.f) * disS[t];
    __syncthreads();                                           // B5

    {   // ---- matvec adj*u -> rowc (row L1; all terms >= 0) ----
        short8 a0 = *(const short8*)&adjB[r][seg * 16];
        short8 a1 = *(const short8*)&adjB[r][seg * 16 + 8];
        float s = 0.f;
#pragma unroll
        for (int j = 0; j < 8; ++j) {
            s += bf2f((ushort)a0[j]) * uS[seg * 16 + j];
            s += bf2f((ushort)a1[j]) * uS[seg * 16 + 8 + j];
        }
        s += __shfl_xor(s, 1, 64);
        s += __shfl_xor(s, 2, 64);
        s += __shfl_xor(s, 4, 64);
        if (seg == 0) {
            float rsum = maskS[r] * disS[r] * (uS[r] + s);
            rowcS[r]   = maskS[r] * disS[r] / fmaxf(rsum, 1e-12f);
        }
    }
    __syncthreads();                                           // B6

    // ---- build ST[m][k] = rowc_k*(adj[k][m]+delta)*u_m (bf16, LDS) ----
    {
        const int m = t & 127, sl = t >> 7, k0 = sl * 16;
        const float um = uS[m];
        float vv[16];
#pragma unroll
        for (int j = 0; j < 16; ++j) {
            int k = k0 + j;
            vv[j] = rowcS[k] * (bf2f(adjB[k][m]) + ((k == m) ? 1.f : 0.f)) * um;
        }
        uint4 p0, p1;
        p0.x = pk2(vv[0],  vv[1]);  p0.y = pk2(vv[2],  vv[3]);
        p0.z = pk2(vv[4],  vv[5]);  p0.w = pk2(vv[6],  vv[7]);
        p1.x = pk2(vv[8],  vv[9]);  p1.y = pk2(vv[10], vv[11]);
        p1.z = pk2(vv[12], vv[13]); p1.w = pk2(vv[14], vv[15]);
        *(uint4*)&STl[m][k0]     = p0;
        *(uint4*)&STl[m][k0 + 8] = p1;
    }
    __syncthreads();                                           // B7

    // ---- wave tiling: 16 waves, each a 16x64 C tile ----
    const int lane = t & 63, w = t >> 6;
    const int l15 = lane & 15, quad = lane >> 4;
    const int mrow  = (w & 7) * 16;
    const int nhalf = (w >> 3) * 64;
    f32x4 acc[4];

    // ---- G2: P = adj * S ----
#pragma unroll
    for (int nt = 0; nt < 4; ++nt) acc[nt] = (f32x4){0.f, 0.f, 0.f, 0.f};
#pragma unroll
    for (int k0 = 0; k0 < 128; k0 += 32) {
        short8 a0 = *(const short8*)&adjB[mrow + l15][k0 + quad * 8];
#pragma unroll
        for (int nt = 0; nt < 4; ++nt) {
            short8 bf = *(const short8*)&STl[nhalf + nt * 16 + l15][k0 + quad * 8];
            acc[nt] = __builtin_amdgcn_mfma_f32_16x16x32_bf16(a0, bf, acc[nt], 0, 0, 0);
        }
    }
    __syncthreads();                                           // B8: adj bf16 dead

    // ---- write P^T (bf16) into adjB region ----
    ushort (*PT)[136] = (ushort(*)[136])&adjB[0][0];
#pragma unroll
    for (int nt = 0; nt < 4; ++nt) {
        int j    = nhalf + nt * 16 + l15;
        int mcol = mrow + quad * 4;
        uint2 w2;
        w2.x = pk2(acc[nt][0], acc[nt][1]);
        w2.y = pk2(acc[nt][2], acc[nt][3]);
        *(uint2*)&PT[j][mcol] = w2;
    }
    __syncthreads();                                           // B9

    // ---- half0 x prefetch: overlaps G3 + nadj stores, drained at B10 ----
    const int xrow = t & 127, kq0 = t >> 7;     // xrow = d-col, kq0 in 0..7
    float xv0[8], xv1[8];
    {
        const float* xb = x + (size_t)b * Nn * Dd + xrow;
#pragma unroll
        for (int k = 0; k < 8; ++k) xv0[k] = xb[(size_t)(8 * kq0 + k) * Dd];
#pragma unroll
        for (int k = 0; k < 8; ++k) xv1[k] = xb[(size_t)(8 * (kq0 + 8) + k) * Dd];
    }

    // ---- G3: nadj = S^T P ----
#pragma unroll
    for (int nt = 0; nt < 4; ++nt) acc[nt] = (f32x4){0.f, 0.f, 0.f, 0.f};
#pragma unroll
    for (int k0 = 0; k0 < 128; k0 += 32) {
        short8 a0 = *(const short8*)&STl[mrow + l15][k0 + quad * 8];
#pragma unroll
        for (int nt = 0; nt < 4; ++nt) {
            short8 bf = *(const short8*)&PT[nhalf + nt * 16 + l15][k0 + quad * 8];
            acc[nt] = __builtin_amdgcn_mfma_f32_16x16x32_bf16(a0, bf, acc[nt], 0, 0, 0);
        }
    }
#pragma unroll
    for (int nt = 0; nt < 4; ++nt)
#pragma unroll
        for (int rr2 = 0; rr2 < 4; ++rr2) {
            int row = mrow + quad * 4 + rr2;
            int col = nhalf + nt * 16 + l15;
            nadj[((size_t)b * Nn + row) * Nn + col] = acc[nt][rr2];
        }
    __syncthreads();                                           // B10: PT dead

    // ---- emb = S^T x; x staged bf16 k-pairs xTp[d][kp] in dead region ----
    uint (*xTp)[68] = (uint(*)[68])&adjB[0][0];   // 128*68*4 = 34816 B
    const int dcb = (w >> 3) * 64;

    // half 0: conflict-free staging writes (uint4 per d-row, lanes vary row)
    {
        uint4 q;
        q.x = pk2(xv0[0], xv0[1]); q.y = pk2(xv0[2], xv0[3]);
        q.z = pk2(xv0[4], xv0[5]); q.w = pk2(xv0[6], xv0[7]);
        *(uint4*)&xTp[xrow][4 * kq0] = q;
        q.x = pk2(xv1[0], xv1[1]); q.y = pk2(xv1[2], xv1[3]);
        q.z = pk2(xv1[4], xv1[5]); q.w = pk2(xv1[6], xv1[7]);
        *(uint4*)&xTp[xrow][4 * (kq0 + 8)] = q;
    }
    __syncthreads();                                           // B11

    // half1 x prefetch: overlaps GEMM h0 + emb h0 stores, drained at B12
    {
        const float* xb = x + (size_t)b * Nn * Dd + 128 + xrow;
#pragma unroll
        for (int k = 0; k < 8; ++k) xv0[k] = xb[(size_t)(8 * kq0 + k) * Dd];
#pragma unroll
        for (int k = 0; k < 8; ++k) xv1[k] = xb[(size_t)(8 * (kq0 + 8) + k) * Dd];
    }

    f32x4 accE[4];
#pragma unroll
    for (int nt = 0; nt < 4; ++nt) accE[nt] = (f32x4){0.f, 0.f, 0.f, 0.f};
#pragma unroll
    for (int ks = 0; ks < 4; ++ks) {
        short8 aE = *(const short8*)&STl[mrow + l15][ks * 32 + quad * 8];
#pragma unroll
        for (int nt = 0; nt < 4; ++nt) {
            short8 bf = *(const short8*)&xTp[dcb + nt * 16 + l15][ks * 16 + quad * 4];
            accE[nt] = __builtin_amdgcn_mfma_f32_16x16x32_bf16(aE, bf, accE[nt], 0, 0, 0);
        }
    }
#pragma unroll
    for (int nt = 0; nt < 4; ++nt)
#pragma unroll
        for (int rr2 = 0; rr2 < 4; ++rr2) {
            int row = mrow + quad * 4 + rr2;
            int col = dcb + nt * 16 + l15;
            emb[((size_t)b * Nn + row) * Dd + col] = accE[nt][rr2];
        }
    __syncthreads();                                           // B12

    // half 1
    {
        uint4 q;
        q.x = pk2(xv0[0], xv0[1]); q.y = pk2(xv0[2], xv0[3]);
        q.z = pk2(xv0[4], xv0[5]); q.w = pk2(xv0[6], xv0[7]);
        *(uint4*)&xTp[xrow][4 * kq0] = q;
        q.x = pk2(xv1[0], xv1[1]); q.y = pk2(xv1[2], xv1[3]);
        q.z = pk2(xv1[4], xv1[5]); q.w = pk2(xv1[6], xv1[7]);
        *(uint4*)&xTp[xrow][4 * (kq0 + 8)] = q;
    }
    __syncthreads();                                           // B13

#pragma unroll
    for (int nt = 0; nt < 4; ++nt) accE[nt] = (f32x4){0.f, 0.f, 0.f, 0.f};
#pragma unroll
    for (int ks = 0; ks < 4; ++ks) {
        short8 aE = *(const short8*)&STl[mrow + l15][ks * 32 + quad * 8];
#pragma unroll
        for (int nt = 0; nt < 4; ++nt) {
            short8 bf = *(const short8*)&xTp[dcb + nt * 16 + l15][ks * 16 + quad * 4];
            accE[nt] = __builtin_amdgcn_mfma_f32_16x16x32_bf16(aE, bf, accE[nt], 0, 0, 0);
        }
    }
#pragma unroll
    for (int nt = 0; nt < 4; ++nt)
#pragma unroll
        for (int rr2 = 0; rr2 < 4; ++rr2) {
            int row = mrow + quad * 4 + rr2;
            int col = 128 + dcb + nt * 16 + l15;
            emb[((size_t)b * Nn + row) * Dd + col] = accE[nt][rr2];
        }
}

extern "C" void kernel_launch(void* const* d_in, const int* in_sizes, int n_in,
                              void* d_out, int out_size, void* d_ws, size_t ws_size,
                              hipStream_t stream)
{
    const float* x     = (const float*)d_in[0];
    const float* adj   = (const float*)d_in[1];
    const int*   head  = (const int*)d_in[2];
    const float* lin_w = (const float*)d_in[3];
    const float* bias  = (const float*)d_in[4];

    float* emb  = (float*)d_out;                 // [B,N,D]
    float* nadj = emb + (size_t)Bsz * Nn * Dd;   // [B,N,N]

    mega<<<Bsz, 1024, 0, stream>>>(x, adj, head, lin_w, bias, emb, nadj);
}